// Round 8
// baseline (275.119 us; speedup 1.0000x reference)
//
#include <hip/hip_runtime.h>
#include <cstddef>
#include <cstdint>

#define N_BATCH 16
#define C_IN    512
#define L       4096
#define KC      256
#define VC      512
#define NH      8
#define HK      32   // KC/NH
#define HV      64   // VC/NH
#define CTX_CHUNKS 8
#define CHUNK_L (L / CTX_CHUNKS)  // 512

using f32x4 = __attribute__((ext_vector_type(4))) float;
using s16x8 = __attribute__((ext_vector_type(8))) short;

// round-to-nearest-even fp32 -> bf16 bits
static __device__ inline ushort f2bf(float f) {
  uint32_t u = __float_as_uint(f);
  uint32_t r = (u + 0x7FFFu + ((u >> 16) & 1u)) >> 16;
  return (ushort)r;
}
static __device__ inline float bf2f(ushort u) {
  return __uint_as_float((uint32_t)u << 16);
}

// ---------------------------------------------------------------------------
// Prep 1: combined bf16 weight matrix Wb[1024][512] + combined bias bb[1024]
// ---------------------------------------------------------------------------
__global__ __launch_bounds__(256) void k_prep_w(
    const float* __restrict__ Wk, const float* __restrict__ bk,
    const float* __restrict__ Wq, const float* __restrict__ bq,
    const float* __restrict__ Wv, const float* __restrict__ bv,
    ushort* __restrict__ Wb, float* __restrict__ bb)
{
  const int o = blockIdx.x;          // 1024
  const float* src; const float* bsrc; int oo;
  if (o < 256)      { src = Wk + (size_t)o * C_IN;         bsrc = bk; oo = o; }
  else if (o < 512) { src = Wq + (size_t)(o - 256) * C_IN; bsrc = bq; oo = o - 256; }
  else              { src = Wv + (size_t)(o - 512) * C_IN; bsrc = bv; oo = o - 512; }
  const int t = threadIdx.x;
  Wb[(size_t)o * C_IN + t * 2]     = f2bf(src[t * 2]);
  Wb[(size_t)o * C_IN + t * 2 + 1] = f2bf(src[t * 2 + 1]);
  if (t == 0) bb[o] = bsrc[oo];
}

// ---------------------------------------------------------------------------
// Prep 2: transpose+cast x (n,512,4096) f32 -> xT (n,4096,512) bf16
// ---------------------------------------------------------------------------
__global__ __launch_bounds__(256) void k_prep_x(const float* __restrict__ x,
                                                ushort* __restrict__ xT)
{
  __shared__ float t[64][65];
  const int n = blockIdx.z, cy = blockIdx.y, lx = blockIdx.x;
  const float* xp = x + ((size_t)n * C_IN + cy * 64) * L + (size_t)lx * 64;
  const int l4 = (threadIdx.x & 15) * 4;
  const int c0 = threadIdx.x >> 4;
  #pragma unroll
  for (int i = 0; i < 4; ++i) {
    int cc = c0 + i * 16;
    f32x4 v = *(const f32x4*)&xp[(size_t)cc * L + l4];
    t[cc][l4]     = v[0];
    t[cc][l4 + 1] = v[1];
    t[cc][l4 + 2] = v[2];
    t[cc][l4 + 3] = v[3];
  }
  __syncthreads();
  ushort* op = xT + ((size_t)n * L + lx * 64) * C_IN + cy * 64;
  const int cp = (threadIdx.x & 15) * 4;
  const int l0 = threadIdx.x >> 4;
  #pragma unroll
  for (int i = 0; i < 4; ++i) {
    int lr = l0 + i * 16;
    uint2 pk;
    pk.x = (uint32_t)f2bf(t[cp][lr])     | ((uint32_t)f2bf(t[cp + 1][lr]) << 16);
    pk.y = (uint32_t)f2bf(t[cp + 2][lr]) | ((uint32_t)f2bf(t[cp + 3][lr]) << 16);
    *(uint2*)(op + (size_t)lr * C_IN + cp) = pk;
  }
}

// ---------------------------------------------------------------------------
// Kernel 1: KQV = Wb @ x + bias, bf16 MFMA, 256x256 tile, BK=64, 8 waves.
// 4-phase/K-tile interleaved schedule with counted vmcnt (T3+T4):
//   phase = { stage 1 half-tile; vmcnt(4); barrier; ds_read subtile;
//             setprio1; 16 MFMA; setprio0; barrier }
// Interleaved fragment mapping: A row of frag f = f*32 + wr*16 + (lane&15);
// B row of frag g = g*64 + wc*16 + (lane&15) -> progressive half-tile use:
//   P1: A-lo + B-lo, P2: B-hi, P3: A-hi, P4: (regs only).
// Stage order of next tile matches: A-lo, B-lo, B-hi, A-hi.
// oy==1 (Q channels): fused channel softmax; wr-halves combined via LDS.
// ---------------------------------------------------------------------------
#define QBM 256
#define QBN 256
#define QBK 64

__global__ __launch_bounds__(512) void k_qkv_mfma(
    const ushort* __restrict__ Wb,   // [1024][512] bf16
    const ushort* __restrict__ xT,   // [n][4096][512] bf16
    const float* __restrict__ bb,    // [1024]
    ushort* __restrict__ kqv,        // [n][1024][4096] bf16 (K,V rows only)
    ushort* __restrict__ qT)         // [n][4096][256] bf16 (normalized Q^T)
{
  extern __shared__ __align__(16) char smem[];
  const int n  = blockIdx.z;
  const int oy = blockIdx.y;   // 4 row tiles of 256
  const int lx = blockIdx.x;   // 16 col tiles of 256
  const int tid  = threadIdx.x;
  const int wave = tid >> 6, lane = tid & 63;
  const int wr = wave >> 2, wc = wave & 3;   // 2 x 4

  f32x4 acc[8][4] = {};

  const ushort* gA = Wb + (size_t)(oy * QBM) * C_IN;
  const ushort* gB = xT + ((size_t)n * L + lx * QBN) * C_IN;

  const int srow8 = lane >> 3;   // 0..7
  const int lane7 = lane & 7;

  // stage one half-tile (128 rows) of operand (isA) at row-half rh (0|128)
  // into buffer buf for K-offset k0.  2 gload_lds per thread; all 8 waves
  // contribute (wave covers rows rh + wave*16 + {0..7, 8..15}).
  #define STAGE_HALF(buf, k0, isA, rh)                                           \
    {                                                                            \
      ushort* S_ = (ushort*)(smem + (buf) * 65536 + ((isA) ? 0 : 32768));        \
      const ushort* G_ = (isA) ? gA : gB;                                        \
      _Pragma("unroll")                                                          \
      for (int i_ = 0; i_ < 2; ++i_) {                                           \
        int rb_ = (rh) + wave * 16 + i_ * 8;                                     \
        int row_ = rb_ + srow8;                                                  \
        int ss_ = lane7 ^ (row_ & 7);                                            \
        __builtin_amdgcn_global_load_lds(                                        \
            (const __attribute__((address_space(1))) uint32_t*)(G_ + (size_t)row_ * C_IN + (k0) + ss_ * 8), \
            (__attribute__((address_space(3))) uint32_t*)(S_ + rb_ * QBK),       \
            16, 0, 0);                                                           \
      }                                                                          \
    }

  #define WAITV(nn) asm volatile("s_waitcnt vmcnt(" #nn ")" ::: "memory")
  #define BARX() do { asm volatile("" ::: "memory");                             \
                      __builtin_amdgcn_s_barrier();                              \
                      asm volatile("" ::: "memory"); } while (0)

  s16x8 afr[4][2], bf01[2][2], bf23[2][2];

  #define READ_A(As_, fbase)                                                     \
    _Pragma("unroll")                                                            \
    for (int q_ = 0; q_ < 4; ++q_)                                               \
      _Pragma("unroll")                                                          \
      for (int ks_ = 0; ks_ < 2; ++ks_) {                                        \
        int row_ = ((fbase) + q_) * 32 + wr * 16 + (lane & 15);                  \
        int slot_ = (ks_ * 4 + (lane >> 4)) ^ (row_ & 7);                        \
        afr[q_][ks_] = *(const s16x8*)&(As_)[row_ * QBK + slot_ * 8];            \
      }
  #define READ_B(Bs_, dst, gbase)                                                \
    _Pragma("unroll")                                                            \
    for (int j_ = 0; j_ < 2; ++j_)                                               \
      _Pragma("unroll")                                                          \
      for (int ks_ = 0; ks_ < 2; ++ks_) {                                        \
        int row_ = ((gbase) + j_) * 64 + wc * 16 + (lane & 15);                  \
        int slot_ = (ks_ * 4 + (lane >> 4)) ^ (row_ & 7);                        \
        dst[j_][ks_] = *(const s16x8*)&(Bs_)[row_ * QBK + slot_ * 8];            \
      }
  #define MFMA_Q(fbase, gbase, bfrag)                                            \
    __builtin_amdgcn_s_setprio(1);                                               \
    _Pragma("unroll")                                                            \
    for (int q_ = 0; q_ < 4; ++q_)                                               \
      _Pragma("unroll")                                                          \
      for (int j_ = 0; j_ < 2; ++j_)                                             \
        _Pragma("unroll")                                                        \
        for (int ks_ = 0; ks_ < 2; ++ks_)                                        \
          acc[(fbase) + q_][(gbase) + j_] = __builtin_amdgcn_mfma_f32_16x16x32_bf16( \
              afr[q_][ks_], bfrag[j_][ks_], acc[(fbase) + q_][(gbase) + j_], 0, 0, 0); \
    __builtin_amdgcn_s_setprio(0);

  // prologue: stage tile 0 in consumption order
  STAGE_HALF(0, 0, 1, 0)     // A-lo
  STAGE_HALF(0, 0, 0, 0)     // B-lo
  STAGE_HALF(0, 0, 0, 128)   // B-hi
  STAGE_HALF(0, 0, 1, 128)   // A-hi

  const int nt = C_IN / QBK;   // 8
  for (int t = 0; t < nt; ++t) {
    const int cb = t & 1, nb = cb ^ 1;
    const int kn = (t + 1) * QBK;
    ushort* As = (ushort*)(smem + cb * 65536);
    ushort* Bs = (ushort*)(smem + cb * 65536 + 32768);
    const bool st = t < nt - 1;
    // ---- P1: quad m0-3 x n0-1 ----
    if (st) STAGE_HALF(nb, kn, 1, 0)
    WAITV(4); BARX();
    READ_A(As, 0) READ_B(Bs, bf01, 0)
    MFMA_Q(0, 0, bf01)
    BARX();
    // ---- P2: quad m0-3 x n2-3 ----
    if (st) { STAGE_HALF(nb, kn, 0, 0) WAITV(4); } else { WAITV(2); }
    BARX();
    READ_B(Bs, bf23, 2)
    MFMA_Q(0, 2, bf23)
    BARX();
    // ---- P3: quad m4-7 x n0-1 ----
    if (st) { STAGE_HALF(nb, kn, 0, 128) WAITV(4); } else { WAITV(0); }
    BARX();
    READ_A(As, 4)
    MFMA_Q(4, 0, bf01)
    BARX();
    // ---- P4: quad m4-7 x n2-3 (register-only) ----
    if (st) STAGE_HALF(nb, kn, 1, 128)
    BARX();
    MFMA_Q(4, 2, bf23)
    BARX();
  }
  #undef STAGE_HALF
  #undef READ_A
  #undef READ_B
  #undef MFMA_Q

  if (oy != 1) {
    // K/V rows: wave-private 16x68 f32 LDS transpose -> uint2 bf16 stores.
    // Frag (m,g) -> row m*32 + wr*16 + [0,16), col g*64 + wc*16 + [0,16).
    float* ep = (float*)smem + wave * (16 * 68);
    const int erow = lane >> 4;   // 0..3
    const int ecol = lane & 15;
    const float* bias = bb + oy * QBM;
    ushort* outp = kqv + ((size_t)n * 1024 + oy * QBM) * L + (size_t)lx * QBN;
    const int grun = ecol >> 2;          // which g-block this lane stores
    const int coff = (ecol & 3) * 4;     // float4 offset within 16-col run
    #pragma unroll
    for (int m = 0; m < 8; ++m) {
      #pragma unroll
      for (int g = 0; g < 4; ++g)
        #pragma unroll
        for (int r = 0; r < 4; ++r)
          ep[(erow * 4 + r) * 68 + g * 16 + ecol] = acc[m][g][r];
      #pragma unroll
      for (int p = 0; p < 4; ++p) {
        int row16 = p * 4 + erow;                 // 0..15
        f32x4 v = *(const f32x4*)&ep[row16 * 68 + ecol * 4];
        int orow = m * 32 + wr * 16 + row16;
        int ocol = grun * 64 + wc * 16 + coff;
        float bo = bias[orow];
        uint2 pk;
        pk.x = (uint32_t)f2bf(v[0] + bo) | ((uint32_t)f2bf(v[1] + bo) << 16);
        pk.y = (uint32_t)f2bf(v[2] + bo) | ((uint32_t)f2bf(v[3] + bo) << 16);
        *(uint2*)&outp[(size_t)orow * L + ocol] = pk;
      }
    }
  } else {
    // Q rows: fused channel softmax over 32 channels of head f = frag m.
    // Wave wr holds channels wr*16 + g4 + r; combine wr halves via LDS.
    const float* bias = bb + 256;
    ushort* qbase = qT + (size_t)n * L * KC;
    const int g4 = (lane >> 4) * 4;
    float* pmax = (float*)smem;            // [8][4][4][16][2] = 16 KB
    float* psum = (float*)smem + 4096;     // 16 KB
    __syncthreads();   // all K-loop LDS traffic done before reuse
    // pass 1: wave-local 16-channel partials
    #pragma unroll
    for (int f = 0; f < 8; ++f) {
      #pragma unroll
      for (int j = 0; j < 4; ++j) {
        float v[4];
        #pragma unroll
        for (int r = 0; r < 4; ++r)
          v[r] = acc[f][j][r] + bias[f * 32 + wr * 16 + g4 + r];
        float mx = fmaxf(fmaxf(v[0], v[1]), fmaxf(v[2], v[3]));
        mx = fmaxf(mx, __shfl_xor(mx, 16));
        mx = fmaxf(mx, __shfl_xor(mx, 32));
        float s = 0.f;
        #pragma unroll
        for (int r = 0; r < 4; ++r) s += __expf(v[r] - mx);
        s += __shfl_xor(s, 16);
        s += __shfl_xor(s, 32);
        int idx = (((f * 4 + j) * 4 + wc) * 16 + (lane & 15)) * 2 + wr;
        pmax[idx] = mx;
        psum[idx] = s;
      }
    }
    __syncthreads();
    // pass 2: combine with other wr-half, normalize, store
    #pragma unroll
    for (int f = 0; f < 8; ++f) {
      #pragma unroll
      for (int j = 0; j < 4; ++j) {
        int idx = (((f * 4 + j) * 4 + wc) * 16 + (lane & 15)) * 2 + wr;
        float mw = pmax[idx],     sw = psum[idx];
        float mo = pmax[idx ^ 1], so = psum[idx ^ 1];
        float M = fmaxf(mw, mo);
        float tot = sw * __expf(mw - M) + so * __expf(mo - M);
        float inv = 1.0f / tot;
        float e[4];
        #pragma unroll
        for (int r = 0; r < 4; ++r)
          e[r] = __expf(acc[f][j][r] + bias[f * 32 + wr * 16 + g4 + r] - M) * inv;
        int l = lx * QBN + j * 64 + wc * 16 + (lane & 15);
        ushort* dst = qbase + (size_t)l * KC + f * 32 + wr * 16 + g4;
        uint2 pk;
        pk.x = (uint32_t)f2bf(e[0]) | ((uint32_t)f2bf(e[1]) << 16);
        pk.y = (uint32_t)f2bf(e[2]) | ((uint32_t)f2bf(e[3]) << 16);
        *(uint2*)dst = pk;
      }
    }
  }
}

// ---------------------------------------------------------------------------
// Reductions
// ---------------------------------------------------------------------------
__device__ inline float blockReduceMax(float v, float* red) {
  #pragma unroll
  for (int off = 32; off > 0; off >>= 1)
    v = fmaxf(v, __shfl_down(v, off, 64));
  int tid = threadIdx.x;
  if ((tid & 63) == 0) red[tid >> 6] = v;
  __syncthreads();
  return fmaxf(fmaxf(red[0], red[1]), fmaxf(red[2], red[3]));
}
__device__ inline float blockReduceSum(float v, float* red) {
  #pragma unroll
  for (int off = 32; off > 0; off >>= 1)
    v += __shfl_down(v, off, 64);
  int tid = threadIdx.x;
  if ((tid & 63) == 0) red[tid >> 6] = v;
  __syncthreads();
  return red[0] + red[1] + red[2] + red[3];
}

// ---------------------------------------------------------------------------
// Kernel 2: K softmax stats over L per (n, row) from bf16 K
// ---------------------------------------------------------------------------
__global__ __launch_bounds__(256) void k_kstats(const ushort* __restrict__ kqv,
                                                float* __restrict__ kmax,
                                                float* __restrict__ kinv)
{
  const int r = blockIdx.x;
  const int n = blockIdx.y;
  const ushort* row = kqv + ((size_t)n * 1024 + r) * L;
  __shared__ float red1[4];
  __shared__ float red2[4];
  const int tid = threadIdx.x;
  s16x8 a = *(const s16x8*)(row + tid * 16);
  s16x8 b = *(const s16x8*)(row + tid * 16 + 8);
  float v[16];
  #pragma unroll
  for (int j = 0; j < 8; ++j) { v[j] = bf2f((ushort)a[j]); v[8 + j] = bf2f((ushort)b[j]); }
  float m = -3.0e38f;
  #pragma unroll
  for (int j = 0; j < 16; ++j) m = fmaxf(m, v[j]);
  m = blockReduceMax(m, red1);
  float s = 0.f;
  #pragma unroll
  for (int j = 0; j < 16; ++j) s += __expf(v[j] - m);
  s = blockReduceSum(s, red2);
  if (tid == 0) { kmax[n * KC + r] = m; kinv[n * KC + r] = 1.0f / s; }
}

// ---------------------------------------------------------------------------
// Kernel 4: context partials via MFMA over l (swizzled LDS)
// ---------------------------------------------------------------------------
__global__ __launch_bounds__(256) void k_ctx_mfma(const ushort* __restrict__ kqv,
                                                  const float* __restrict__ kmax,
                                                  const float* __restrict__ kinv,
                                                  float* __restrict__ ctxpart)
{
  const int chunk = blockIdx.x;   // 8
  const int nh    = blockIdx.y;   // 128
  const int n = nh >> 3, h = nh & 7;
  const int tid = threadIdx.x, wave = tid >> 6, lane = tid & 63;

  __shared__ __align__(16) ushort Ks[32 * 64];
  __shared__ __align__(16) ushort Vs[64 * 64];
  __shared__ float km[32], kv[32];

  if (tid < 32) { km[tid] = kmax[nh * 32 + tid]; kv[tid] = kinv[nh * 32 + tid]; }
  __syncthreads();

  const ushort* Kp = kqv + ((size_t)n * 1024 + h * HK) * L + (size_t)chunk * CHUNK_L;
  const ushort* Vp = kqv + ((size_t)n * 1024 + 512 + h * HV) * L + (size_t)chunk * CHUNK_L;

  const int krow = tid >> 3;
  const int kslot = (tid & 7) ^ (krow & 7);
  f32x4 acc[2] = {};

  for (int step = 0; step < 8; ++step) {
    const int l0 = step * 64;
    #pragma unroll
    for (int j = 0; j < 2; ++j) {
      int vr = (j * 4 + wave) * 8 + (lane >> 3);
      int vslot = (lane & 7) ^ (vr & 7);
      __builtin_amdgcn_global_load_lds(
          (const __attribute__((address_space(1))) uint32_t*)(Vp + (size_t)vr * L + l0 + vslot * 8),
          (__attribute__((address_space(3))) uint32_t*)(Vs + (size_t)(j * 4 + wave) * 512),
          16, 0, 0);
    }
    s16x8 kvec = *(const s16x8*)(Kp + (size_t)krow * L + l0 + (tid & 7) * 8);
    float mk = km[krow], ik = kv[krow];
    s16x8 w;
    #pragma unroll
    for (int j = 0; j < 8; ++j) {
      float f = bf2f((ushort)kvec[j]);
      w[j] = (short)f2bf(__expf(f - mk) * ik);
    }
    *(s16x8*)&Ks[krow * 64 + kslot * 8] = w;
    __syncthreads();

    #pragma unroll
    for (int ks = 0; ks < 2; ++ks) {
      int arow = wave * 16 + (lane & 15);
      int aslot = (ks * 4 + (lane >> 4)) ^ (arow & 7);
      s16x8 af = *(const s16x8*)&Vs[arow * 64 + aslot * 8];
      #pragma unroll
      for (int nf = 0; nf < 2; ++nf) {
        int brow = nf * 16 + (lane & 15);
        int bslot = (ks * 4 + (lane >> 4)) ^ (brow & 7);
        s16x8 bfr = *(const s16x8*)&Ks[brow * 64 + bslot * 8];
        acc[nf] = __builtin_amdgcn_mfma_f32_16x16x32_bf16(af, bfr, acc[nf], 0, 0, 0);
      }
    }
    __syncthreads();
  }

  float* outp = ctxpart + ((size_t)nh * CTX_CHUNKS + chunk) * (HV * HK);
  #pragma unroll
  for (int nf = 0; nf < 2; ++nf) {
    #pragma unroll
    for (int r = 0; r < 4; ++r) {
      int v = wave * 16 + (lane >> 4) * 4 + r;
      int k = nf * 16 + (lane & 15);
      outp[v * HK + k] = acc[nf][r];
    }
  }
}

// ---------------------------------------------------------------------------
// Kernel 5: reduce ctx partials; fold We; write bf16 Mbuf [n][512][256]
// ---------------------------------------------------------------------------
__global__ __launch_bounds__(256) void k_m(const float* __restrict__ ctxpart,
                                           const float* __restrict__ We,
                                           ushort* __restrict__ Mbuf)
{
  const int h = blockIdx.x;
  const int n = blockIdx.y;
  const int nh = n * 8 + h;
  const int tid = threadIdx.x;
  __shared__ float ctx[64][32];

  #pragma unroll
  for (int i = 0; i < 8; ++i) {
    int e = tid + i * 256;
    float s = 0.f;
    for (int c = 0; c < CTX_CHUNKS; ++c)
      s += ctxpart[((size_t)nh * CTX_CHUNKS + c) * (HV * HK) + e];
    ((float*)ctx)[e] = s;
  }
  __syncthreads();

  const int k  = tid & 31;
  const int og = tid >> 5;
  for (int j = 0; j < 64; ++j) {
    int o = og * 64 + j;
    const float* we = We + (size_t)o * VC + h * HV;
    float s = 0.f;
    #pragma unroll
    for (int v = 0; v < 64; ++v) s += we[v] * ctx[v][k];
    Mbuf[((size_t)n * 512 + o) * KC + h * HK + k] = f2bf(s);
  }
}

// ---------------------------------------------------------------------------
// Kernel 6: out = x + be + M @ q_smT via MFMA.  M=512, N=4096(l), K=256.
// 128x128 tile, BK=32, 2-buffer counted-vmcnt pipeline (vmcnt(4)).
// ---------------------------------------------------------------------------
#define BM 128
#define BN 128
#define BK 32

__global__ __launch_bounds__(256) void k_final_mfma(
    const ushort* __restrict__ Mb,   // [n][512][256] bf16
    const ushort* __restrict__ qT,   // [n][4096][256] bf16
    const float* __restrict__ x,
    const float* __restrict__ be,
    float* __restrict__ out)
{
  const int n  = blockIdx.z;
  const int oy = blockIdx.y;   // 4
  const int lx = blockIdx.x;   // 32
  const int tid  = threadIdx.x;
  const int wave = tid >> 6, lane = tid & 63;
  const int wr = wave >> 1, wc = wave & 1;

  __shared__ __align__(16) char smem[32768 + 17408];

  f32x4 acc[4][4] = {};

  const ushort* gA = Mb + ((size_t)n * 512 + oy * BM) * KC;
  const ushort* gB = qT + ((size_t)n * L + lx * BN) * KC;

  const int r0 = wave * 32;
  const int lrow = lane >> 2;

  #define FSTAGE(buf, k0)                                                        \
    {                                                                            \
      ushort* As_ = (ushort*)(smem + (buf) * 16384);                             \
      ushort* Bs_ = (ushort*)(smem + (buf) * 16384 + 8192);                      \
      _Pragma("unroll")                                                          \
      for (int i_ = 0; i_ < 2; ++i_) {                                           \
        int row_ = r0 + i_ * 16 + lrow;                                          \
        int ss_ = (lane & 3) ^ ((row_ >> 1) & 3);                                \
        __builtin_amdgcn_global_load_lds(                                        \
            (const __attribute__((address_space(1))) uint32_t*)(gA + (size_t)row_ * KC + (k0) + ss_ * 8), \
            (__attribute__((address_space(3))) uint32_t*)(As_ + (r0 + i_ * 16) * BK), \
            16, 0, 0);                                                           \
        __builtin_amdgcn_global_load_lds(                                        \
            (const __attribute__((address_space(1))) uint32_t*)(gB + (size_t)row_ * KC + (k0) + ss_ * 8), \
            (__attribute__((address_space(3))) uint32_t*)(Bs_ + (r0 + i_ * 16) * BK), \
            16, 0, 0);                                                           \
      }                                                                          \
    }

  FSTAGE(0, 0)

  const int nt = KC / BK;   // 8
  for (int t = 0; t < nt; ++t) {
    if (t < nt - 1) {
      FSTAGE((t + 1) & 1, (t + 1) * BK)
      asm volatile("s_waitcnt vmcnt(4)" ::: "memory");
    } else {
      asm volatile("s_waitcnt vmcnt(0)" ::: "memory");
    }
    __builtin_amdgcn_s_barrier();
    asm volatile("" ::: "memory");
    ushort* As = (ushort*)(smem + (t & 1) * 16384);
    ushort* Bs = (ushort*)(smem + (t & 1) * 16384 + 8192);
    s16x8 af[4], bfr[4];
    #pragma unroll
    for (int m = 0; m < 4; ++m) {
      int row = wr * 64 + m * 16 + (lane & 15);
      int slot = (lane >> 4) ^ ((row >> 1) & 3);
      af[m] = *(const s16x8*)&As[row * BK + slot * 8];
    }
    #pragma unroll
    for (int nn = 0; nn < 4; ++nn) {
      int row = wc * 64 + nn * 16 + (lane & 15);
      int slot = (lane >> 4) ^ ((row >> 1) & 3);
      bfr[nn] = *(const s16x8*)&Bs[row * BK + slot * 8];
    }
    __builtin_amdgcn_s_setprio(1);
    #pragma unroll
    for (int m = 0; m < 4; ++m)
      #pragma unroll
      for (int nn = 0; nn < 4; ++nn)
        acc[m][nn] = __builtin_amdgcn_mfma_f32_16x16x32_bf16(af[m], bfr[nn], acc[m][nn], 0, 0, 0);
    __builtin_amdgcn_s_setprio(0);
    asm volatile("" ::: "memory");
    __builtin_amdgcn_s_barrier();
  }
  #undef FSTAGE

  float* ep = (float*)(smem + 32768) + wave * (16 * 68);
  const int erow = lane >> 4;
  const int ecol = lane & 15;
  const float* bias = be + oy * BM + wr * 64;
  const float* xp = x + ((size_t)n * 512 + oy * BM + wr * 64) * L
                  + (size_t)lx * BN + wc * 64;
  float* op = out + ((size_t)n * 512 + oy * BM + wr * 64) * L
            + (size_t)lx * BN + wc * 64;
  #pragma unroll
  for (int m = 0; m < 4; ++m) {
    #pragma unroll
    for (int nn = 0; nn < 4; ++nn)
      #pragma unroll
      for (int r = 0; r < 4; ++r)
        ep[(erow * 4 + r) * 68 + nn * 16 + ecol] = acc[m][nn][r];
    #pragma unroll
    for (int p = 0; p < 4; ++p) {
      int row = p * 4 + erow;
      f32x4 v = *(const f32x4*)&ep[row * 68 + ecol * 4];
      float bo = bias[m * 16 + row];
      f32x4 xv = *(const f32x4*)&xp[(size_t)(m * 16 + row) * L + ecol * 4];
      v = v + xv + bo;
      *(f32x4*)&op[(size_t)(m * 16 + row) * L + ecol * 4] = v;
    }
  }
}

// ---------------------------------------------------------------------------
extern "C" void kernel_launch(void* const* d_in, const int* in_sizes, int n_in,
                              void* d_out, int out_size, void* d_ws, size_t ws_size,
                              hipStream_t stream)
{
  const float* x  = (const float*)d_in[0];
  const float* Wk = (const float*)d_in[1];
  const float* bk = (const float*)d_in[2];
  const float* Wq = (const float*)d_in[3];
  const float* bq = (const float*)d_in[4];
  const float* Wv = (const float*)d_in[5];
  const float* bv = (const float*)d_in[6];
  const float* We = (const float*)d_in[7];
  const float* be = (const float*)d_in[8];
  float* out = (float*)d_out;

  char* ws = (char*)d_ws;
  size_t off = 0;
  ushort* kqv  = (ushort*)(ws + off); off += (size_t)N_BATCH * 1024 * L * 2;
  ushort* xT   = (ushort*)(ws + off); off += (size_t)N_BATCH * L * C_IN * 2;
  ushort* Wb   = (ushort*)(ws + off); off += (size_t)1024 * C_IN * 2;
  float*  bb   = (float*)(ws + off);  off += (size_t)1024 * 4;
  float*  kmax = (float*)(ws + off);  off += (size_t)N_BATCH * KC * 4;
  float*  kinv = (float*)(ws + off);  off += (size_t)N_BATCH * KC * 4;
  ushort* qT   = (ushort*)(ws + off); off += (size_t)N_BATCH * L * KC * 2;
  float*  ctxp = (float*)(ws + off);  off += (size_t)N_BATCH * NH * CTX_CHUNKS * HV * HK * 4;
  ushort* Mbuf = (ushort*)(ws + off); off += (size_t)N_BATCH * 512 * KC * 2;

  (void)hipFuncSetAttribute((const void*)k_qkv_mfma,
                            hipFuncAttributeMaxDynamicSharedMemorySize, 131072);

  k_prep_w<<<dim3(1024), 256, 0, stream>>>(Wk, bk, Wq, bq, Wv, bv, Wb, bb);
  k_prep_x<<<dim3(64, 8, N_BATCH), 256, 0, stream>>>(x, xT);
  k_qkv_mfma<<<dim3(16, 4, N_BATCH), 512, 131072, stream>>>(Wb, xT, bb, kqv, qT);
  k_kstats<<<dim3(KC, N_BATCH), 256, 0, stream>>>(kqv, kmax, kinv);
  k_ctx_mfma<<<dim3(CTX_CHUNKS, N_BATCH * NH), 256, 0, stream>>>(kqv, kmax, kinv, ctxp);
  k_m<<<dim3(NH, N_BATCH), 256, 0, stream>>>(ctxp, We, Mbuf);
  k_final_mfma<<<dim3(32, 4, N_BATCH), 256, 0, stream>>>(Mbuf, qT, x, be, out);
}